// Round 1
// baseline (718.678 us; speedup 1.0000x reference)
//
#include <hip/hip_runtime.h>
#include <math.h>

#define NB 64
#define NN 4096
#define NF 256
#define ND 128
#define NK 8
#define NCHUNK 16
#define CHROWS 256   // NN / NCHUNK
#define MT 64        // rows per block in ln_project_mfma

typedef unsigned int uint;
typedef unsigned short ushort;
typedef __attribute__((ext_vector_type(8))) short short8;
typedef __attribute__((ext_vector_type(4))) float floatx4;

constexpr float LN_EPS_C   = 1e-5f;
constexpr float EPS_ATTN_C = 1e-8f;
constexpr float INV_SCALE  = 0.08838834764831845f; // 1/sqrt(128)

__device__ __forceinline__ float sigmoidf_(float x) { return 1.f / (1.f + expf(-x)); }
__device__ __forceinline__ ushort f2bf(float x) {
    uint u = __float_as_uint(x);
    return (ushort)((u + 0x7FFFu + ((u >> 16) & 1u)) >> 16);
}
__device__ __forceinline__ float bflo(uint u) { return __uint_as_float(u << 16); }
__device__ __forceinline__ float bfhi(uint u) { return __uint_as_float(u & 0xFFFF0000u); }

// ---------------------------------------------------------------- slot init
__global__ void init_slots_k(const float* __restrict__ init, float* __restrict__ slots) {
    int i = blockIdx.x * 256 + threadIdx.x;      // 65536 total
    slots[i] = init[i & (NK * ND - 1)];
}

// ---- weight convert into fragment-contiguous layout:
// wt2 uint4 index = (c16*8 + ks)*64 + lane ; elems j=0..7:
//   col c = c16*16 + (lane&15), f = ks*32 + (lane>>4)*8 + j
// grid: 128 blocks x 64 threads
__global__ void wconv_k(const float* __restrict__ Wk, const float* __restrict__ Wv,
                        ushort* __restrict__ wt2) {
    int idx = blockIdx.x * 64 + threadIdx.x;    // 0..8191 (uint4 index)
    int c16 = idx >> 9, ks = (idx >> 6) & 7, lane = idx & 63;
    int c = c16 * 16 + (lane & 15);
    int f0 = ks * 32 + (lane >> 4) * 8;
    ushort tmp[8];
#pragma unroll
    for (int j = 0; j < 8; ++j) {
        int f = f0 + j;
        float v = (c < ND) ? Wk[(size_t)f * ND + c] : Wv[(size_t)f * ND + (c - ND)];
        tmp[j] = f2bf(v);
    }
    *(uint4*)(wt2 + (size_t)idx * 8) = *(uint4*)tmp;
}

// -------------------- fused LN(inputs) + [x@Wk, x@Wv] via bf16 MFMA
// k out: transposed bf16-pair planes kT2[b][d2][n]  (uint = bf16(2*d2),bf16(2*d2+1))
// v out: row-major bf16 [b][n][d]
// grid: (B*N)/MT = 4096 blocks, 256 threads (4 waves)
__global__ __launch_bounds__(256) void ln_project_mfma(
    const float* __restrict__ inp, const ushort* __restrict__ wt2,
    const float* __restrict__ lw, const float* __restrict__ lb,
    uint* __restrict__ kt2, ushort* __restrict__ vout) {
    __shared__ ushort As[MT][264];   // 33 KB; row stride 528 B
    int t = threadIdx.x;
    size_t rowbase = (size_t)blockIdx.x * MT;
    size_t bidx = rowbase >> 12;          // batch (NN=4096 rows per batch)
    size_t nbase = rowbase & (NN - 1);    // local token base within batch

    // ---- LN phase: 16 threads/row, 16 rows/pass, 4 passes; bf16 to LDS
    {
        int rloc = t >> 4, seg = t & 15;
        const float4* lw4 = (const float4*)lw;
        const float4* lb4 = (const float4*)lb;
#pragma unroll
        for (int p = 0; p < 4; ++p) {
            int r = p * 16 + rloc;
            const float4* rowp = (const float4*)(inp + (rowbase + r) * NF);
            float4 xv[4];
            float sum = 0.f, sq = 0.f;
#pragma unroll
            for (int i = 0; i < 4; ++i) {
                xv[i] = rowp[seg * 4 + i];
                sum += xv[i].x + xv[i].y + xv[i].z + xv[i].w;
                sq += xv[i].x * xv[i].x + xv[i].y * xv[i].y + xv[i].z * xv[i].z + xv[i].w * xv[i].w;
            }
#pragma unroll
            for (int m = 8; m >= 1; m >>= 1) {
                sum += __shfl_xor(sum, m, 64);
                sq  += __shfl_xor(sq,  m, 64);
            }
            float mu = sum * (1.f / NF);
            float var = sq * (1.f / NF) - mu * mu;
            float rs = rsqrtf(var + LN_EPS_C);
#pragma unroll
            for (int i = 0; i < 4; ++i) {
                float4 w = lw4[seg * 4 + i], bb = lb4[seg * 4 + i], x = xv[i];
                float o0 = (x.x - mu) * rs * w.x + bb.x;
                float o1 = (x.y - mu) * rs * w.y + bb.y;
                float o2 = (x.z - mu) * rs * w.z + bb.z;
                float o3 = (x.w - mu) * rs * w.w + bb.w;
                uint2 pk;
                pk.x = (uint)f2bf(o0) | ((uint)f2bf(o1) << 16);
                pk.y = (uint)f2bf(o2) | ((uint)f2bf(o3) << 16);
                *(uint2*)&As[r][seg * 16 + i * 4] = pk;
            }
        }
    }
    __syncthreads();

    // ---- MFMA phase: wave w covers output cols [w*64, w*64+64) of [k|v]
    int w = t >> 6, lane = t & 63;
    int frow = lane & 15, q = lane >> 4;
    floatx4 acc[4][4];
#pragma unroll
    for (int mt = 0; mt < 4; ++mt)
#pragma unroll
        for (int nt = 0; nt < 4; ++nt) acc[mt][nt] = (floatx4)0.f;

#pragma unroll
    for (int ks = 0; ks < 8; ++ks) {
        short8 a[4], b[4];
#pragma unroll
        for (int nt = 0; nt < 4; ++nt)
            b[nt] = *(const short8*)(wt2 + ((((size_t)(w * 4 + nt) * 8 + ks) * 64 + lane) * 8));
#pragma unroll
        for (int mt = 0; mt < 4; ++mt)
            a[mt] = *(const short8*)&As[mt * 16 + frow][ks * 32 + q * 8];
#pragma unroll
        for (int mt = 0; mt < 4; ++mt)
#pragma unroll
            for (int nt = 0; nt < 4; ++nt)
                acc[mt][nt] = __builtin_amdgcn_mfma_f32_16x16x32_bf16(a[mt], b[nt], acc[mt][nt], 0, 0, 0);
    }

    __syncthreads();   // all A-frag reads done before As is reused for v repack

    // C/D layout: col=lane&15 (frow), row=q*4+reg
    if (w < 2) {
        // ---- k epilogue: transpose to kT2[b][d2][n_local] via lane-pair exchange
        int cbase = w * 64;
#pragma unroll
        for (int mt = 0; mt < 4; ++mt)
#pragma unroll
            for (int nt = 0; nt < 4; ++nt) {
                int c = cbase + nt * 16 + frow;
                uint u01 = (uint)f2bf(acc[mt][nt][0]) | ((uint)f2bf(acc[mt][nt][1]) << 16);
                uint u23 = (uint)f2bf(acc[mt][nt][2]) | ((uint)f2bf(acc[mt][nt][3]) << 16);
                uint p01 = __shfl_xor(u01, 1, 64);
                uint p23 = __shfl_xor(u23, 1, 64);
                if ((frow & 1) == 0) {
                    uint4 out;
                    out.x = (u01 & 0xFFFFu) | (p01 << 16);
                    out.y = (u01 >> 16) | (p01 & 0xFFFF0000u);
                    out.z = (u23 & 0xFFFFu) | (p23 << 16);
                    out.w = (u23 >> 16) | (p23 & 0xFFFF0000u);
                    size_t nloc = nbase + mt * 16 + q * 4;
                    *(uint4*)(kt2 + (bidx * 64 + (size_t)(c >> 1)) * NN + nloc) = out;
                }
            }
    } else {
        // ---- v epilogue: park in As (bf16), repack below
        int cbase = (w & 1) * 64;
#pragma unroll
        for (int mt = 0; mt < 4; ++mt)
#pragma unroll
            for (int nt = 0; nt < 4; ++nt) {
                int c = cbase + nt * 16 + frow;
#pragma unroll
                for (int i = 0; i < 4; ++i)
                    As[mt * 16 + q * 4 + i][c] = f2bf(acc[mt][nt][i]);
            }
    }
    __syncthreads();

    // ---- v repack: all 256 threads, coalesced uint4 stores
    {
        int r = t >> 2, part = t & 3;
#pragma unroll
        for (int u = 0; u < 4; ++u) {
            uint4 val = *(const uint4*)&As[r][part * 32 + u * 8];
            *(uint4*)(vout + (rowbase + r) * ND + part * 32 + u * 8) = val;
        }
    }
}

// ------------------------------------------------- q = LN(slots) @ Wq (iter 0)
__global__ __launch_bounds__(64) void q_kernel(
    const float* __restrict__ slots, const float* __restrict__ Wq,
    const float* __restrict__ lw, const float* __restrict__ lb,
    float* __restrict__ qout) {
    __shared__ float sln[ND];
    int bk = blockIdx.x;
    int t = threadIdx.x;
    const float* sp = slots + (size_t)bk * ND;
    float s0 = sp[t], s1 = sp[t + 64];
    float sum = s0 + s1, sq = s0 * s0 + s1 * s1;
#pragma unroll
    for (int m = 1; m < 64; m <<= 1) {
        sum += __shfl_xor(sum, m, 64);
        sq  += __shfl_xor(sq,  m, 64);
    }
    float mu = sum * (1.f / ND);
    float var = sq * (1.f / ND) - mu * mu;
    float rs = rsqrtf(var + LN_EPS_C);
    sln[t]      = (s0 - mu) * rs * lw[t]      + lb[t];
    sln[t + 64] = (s1 - mu) * rs * lw[t + 64] + lb[t + 64];
    __syncthreads();
    float q0 = 0.f, q1 = 0.f;
    for (int dd = 0; dd < ND; ++dd) {
        float v = sln[dd];
        q0 += v * Wq[dd * ND + t];
        q1 += v * Wq[dd * ND + 64 + t];
    }
    qout[(size_t)bk * ND + t] = q0;
    qout[(size_t)bk * ND + 64 + t] = q1;
}

// ------------- attention pass: logits -> softmax(K) -> partial U, S per chunk
// k is transposed bf16-pair planes; v row-major bf16.
// grid: (NCHUNK, NB), 256 threads
// Phase B: rows split across the 4 waves (v read once, not 4x); S-reduction
// fused into phase A via in-register butterfly (no 8-barrier LDS tree).
__global__ __launch_bounds__(256) void attn_kernel(
    const uint* __restrict__ kt2, const ushort* __restrict__ vbuf,
    const float* __restrict__ qbuf, float* __restrict__ pU,
    float* __restrict__ pS) {
    __shared__ __align__(16) float attn_s[CHROWS * NK];   // 8 KB
    __shared__ __align__(16) float qs2[64 * 16];          // 4 KB: [d2][kk][2]
    __shared__ __align__(16) float red_s[4][16][64];      // 16 KB cross-wave U reduce
    __shared__ float sS[4][NK];
    int t = threadIdx.x;
    int chunk = blockIdx.x, b = blockIdx.y;
    int n = chunk * CHROWS + t;
    int w = t >> 6, lane = t & 63;

    // build qs2[d2*16 + kk*2 + (d&1)] = q[kk][d]
#pragma unroll
    for (int p = 0; p < 4; ++p) {
        int idx = p * 256 + t;
        int kk = idx >> 7, d = idx & 127;
        qs2[(d >> 1) * 16 + kk * 2 + (d & 1)] = qbuf[(size_t)b * NK * ND + idx];
    }
    __syncthreads();

    // ---- phase A: logits + softmax over K (thread = token, coalesced k loads)
    {
        const uint* ktp = kt2 + (size_t)b * 64 * NN + n;
        float lg[NK];
#pragma unroll
        for (int kk = 0; kk < NK; ++kk) lg[kk] = 0.f;
#pragma unroll 8
        for (int j = 0; j < 64; ++j) {
            uint kr = ktp[(size_t)j * NN];
            float k0 = bflo(kr), k1 = bfhi(kr);
            const float4* qp = (const float4*)(qs2 + j * 16);
#pragma unroll
            for (int c = 0; c < 4; ++c) {
                float4 qq = qp[c];
                lg[2 * c]     += k0 * qq.x + k1 * qq.y;
                lg[2 * c + 1] += k0 * qq.z + k1 * qq.w;
            }
        }
        float mx = -1e30f;
#pragma unroll
        for (int kk = 0; kk < NK; ++kk) { lg[kk] *= INV_SCALE; mx = fmaxf(mx, lg[kk]); }
        float se = 0.f;
        float e[NK];
#pragma unroll
        for (int kk = 0; kk < NK; ++kk) { e[kk] = expf(lg[kk] - mx); se += e[kk]; }
        float inv = 1.f / se;
#pragma unroll
        for (int kk = 0; kk < NK; ++kk) e[kk] = e[kk] * inv + EPS_ATTN_C;
        ((float4*)attn_s)[t * 2]     = make_float4(e[0], e[1], e[2], e[3]);
        ((float4*)attn_s)[t * 2 + 1] = make_float4(e[4], e[5], e[6], e[7]);

        // fused S-partial: butterfly token-sum within each wave (replaces LDS tree)
#pragma unroll
        for (int m = 1; m < 64; m <<= 1) {
#pragma unroll
            for (int kk = 0; kk < NK; ++kk) e[kk] += __shfl_xor(e[kk], m, 64);
        }
        if (lane == 0) {
#pragma unroll
            for (int kk = 0; kk < NK; ++kk) sS[w][kk] = e[kk];
        }
    }
    __syncthreads();

    // ---- phase B: wave w owns rows [w*64, w*64+64); lane -> d pair (d0=2*lane)
    // each v row is read exactly once per block; 16 accumulators (8 kk x 2 d)
    {
        float ua[16];
#pragma unroll
        for (int a = 0; a < 16; ++a) ua[a] = 0.f;
        const uint* vp = (const uint*)(vbuf + ((size_t)b * NN + (size_t)chunk * CHROWS + w * 64) * ND) + lane;
        const float4* ap = (const float4*)(attn_s + (w * 64) * NK);
        for (int nn2 = 0; nn2 < 64; ++nn2) {
            uint vr = vp[(size_t)nn2 * (ND / 2)];
            float v0 = bflo(vr), v1 = bfhi(vr);
            float4 aA = ap[nn2 * 2];        // attn[row][0..3] (broadcast)
            float4 aB = ap[nn2 * 2 + 1];    // attn[row][4..7]
            ua[0]  += aA.x * v0; ua[1]  += aA.x * v1;
            ua[2]  += aA.y * v0; ua[3]  += aA.y * v1;
            ua[4]  += aA.z * v0; ua[5]  += aA.z * v1;
            ua[6]  += aA.w * v0; ua[7]  += aA.w * v1;
            ua[8]  += aB.x * v0; ua[9]  += aB.x * v1;
            ua[10] += aB.y * v0; ua[11] += aB.y * v1;
            ua[12] += aB.z * v0; ua[13] += aB.z * v1;
            ua[14] += aB.w * v0; ua[15] += aB.w * v1;
        }
#pragma unroll
        for (int a = 0; a < 16; ++a) red_s[w][a][lane] = ua[a];
    }
    __syncthreads();

    // ---- final: cross-wave reduce -> pU; sS reduce -> pS
    {
        size_t pb = ((size_t)chunk * NB + b) * (NK * ND);
#pragma unroll
        for (int i = 0; i < 4; ++i) {
            int slot = i * 256 + t;
            int a = slot >> 6, l = slot & 63;
            float s = red_s[0][a][l] + red_s[1][a][l] + red_s[2][a][l] + red_s[3][a][l];
            int kk = a >> 1, r = a & 1;
            pU[pb + (size_t)kk * ND + 2 * l + r] = s;
        }
        if (t < NK) pS[((size_t)chunk * NB + b) * NK + t] = sS[0][t] + sS[1][t] + sS[2][t] + sS[3][t];
    }
}

// -------- reduce partials, normalize, GRU, LN, MLP residual, (+ next q)
// 256 threads: t = (half, d); serial mat-vec loops split 2-way across halves.
__global__ __launch_bounds__(256) void finish_kernel(
    const float* __restrict__ pU, const float* __restrict__ pS,
    const float* __restrict__ slots_in, const float* __restrict__ wi,
    const float* __restrict__ wh, const float* __restrict__ bi,
    const float* __restrict__ bh, const float* __restrict__ lnw,
    const float* __restrict__ lnb, const float* __restrict__ w1,
    const float* __restrict__ b1, const float* __restrict__ w2,
    const float* __restrict__ b2, float* __restrict__ slots_out,
    const float* __restrict__ Wq, const float* __restrict__ lqw,
    const float* __restrict__ lqb, float* __restrict__ qout, int compute_q) {
    __shared__ float updL[ND], spL[ND], lnL[ND], hL[2 * ND], lnQ[ND];
    __shared__ float part[6][2][ND];   // GRU partial sums (6 KB)
    __shared__ float Up[2][ND], odp[2][ND], qp_[2][ND];
    __shared__ float red[2], red2[2];
    int bk = blockIdx.x;
    int b = bk >> 3, kk = bk & 7;
    int t = threadIdx.x;
    int d = t & 127, half = t >> 7;

    // ---- U (chunk-split across halves), S (broadcast, cheap)
    float U = 0.f;
#pragma unroll
    for (int c = half * 8; c < half * 8 + 8; ++c)
        U += pU[((size_t)c * NB + b) * (NK * ND) + kk * ND + d];
    Up[half][d] = U;
    float S = 0.f;
#pragma unroll
    for (int c = 0; c < NCHUNK; ++c) S += pS[((size_t)c * NB + b) * NK + kk];
    float spd = slots_in[(size_t)bk * ND + d];
    if (half == 0) spL[d] = spd;
    __syncthreads();
    float upd = (Up[0][d] + Up[1][d]) / S;
    if (half == 0) updL[d] = upd;
    __syncthreads();

    // ---- GRU: dd-loop split across halves (64 iters each)
    float a0 = 0.f, a1 = 0.f, a2 = 0.f, a3 = 0.f, a4 = 0.f, a5 = 0.f;
    {
        int dd0 = half * 64;
        for (int dd = dd0; dd < dd0 + 64; ++dd) {
            float u = updL[dd], s = spL[dd];
            const float* wip = wi + (size_t)dd * 3 * ND;
            const float* whp = wh + (size_t)dd * 3 * ND;
            a0 += u * wip[d];          a3 += s * whp[d];
            a1 += u * wip[ND + d];     a4 += s * whp[ND + d];
            a2 += u * wip[2 * ND + d]; a5 += s * whp[2 * ND + d];
        }
    }
    part[0][half][d] = a0; part[1][half][d] = a1; part[2][half][d] = a2;
    part[3][half][d] = a3; part[4][half][d] = a4; part[5][half][d] = a5;
    __syncthreads();
    float gxr = bi[d]          + part[0][0][d] + part[0][1][d];
    float gxz = bi[ND + d]     + part[1][0][d] + part[1][1][d];
    float gxn = bi[2 * ND + d] + part[2][0][d] + part[2][1][d];
    float ghr = bh[d]          + part[3][0][d] + part[3][1][d];
    float ghz = bh[ND + d]     + part[4][0][d] + part[4][1][d];
    float ghn = bh[2 * ND + d] + part[5][0][d] + part[5][1][d];
    float r_ = sigmoidf_(gxr + ghr);
    float z_ = sigmoidf_(gxz + ghz);
    float nn_ = tanhf(gxn + r_ * ghn);
    float snew = (1.f - z_) * nn_ + z_ * spd;   // both halves compute identical snew

    // ---- LN(snew): reduce on half 0's two waves only
    if (half == 0) {
        int wid = d >> 6;
        float sum = snew, sq = snew * snew;
#pragma unroll
        for (int m = 1; m < 64; m <<= 1) {
            sum += __shfl_xor(sum, m, 64);
            sq  += __shfl_xor(sq,  m, 64);
        }
        if ((d & 63) == 0) { red[wid] = sum; red2[wid] = sq; }
    }
    __syncthreads();
    {
        float tot = red[0] + red[1], totq = red2[0] + red2[1];
        float mu = tot * (1.f / ND);
        float var = totq * (1.f / ND) - mu * mu;
        float rs = rsqrtf(var + LN_EPS_C);
        if (half == 0) lnL[d] = (snew - mu) * rs * lnw[d] + lnb[d];
    }
    __syncthreads();

    // ---- MLP1: one output per thread (256 outputs)
    {
        float h0 = b1[t];
        for (int dd = 0; dd < ND; ++dd) h0 += lnL[dd] * w1[(size_t)dd * 2 * ND + t];
        hL[t] = fmaxf(h0, 0.f);
    }
    __syncthreads();

    // ---- MLP2: j-loop split across halves
    {
        float od_p = 0.f;
        int j0 = half * ND;
        for (int j = j0; j < j0 + ND; ++j) od_p += hL[j] * w2[(size_t)j * ND + d];
        odp[half][d] = od_p;
    }
    __syncthreads();
    float od = snew + b2[d] + odp[0][d] + odp[1][d];
    if (half == 0) slots_out[(size_t)bk * ND + d] = od;

    if (compute_q) {
        // ---- LN(od) (reuse red/red2: all prior reads complete past last barrier)
        if (half == 0) {
            int wid = d >> 6;
            float s2 = od, q2 = od * od;
#pragma unroll
            for (int m = 1; m < 64; m <<= 1) {
                s2 += __shfl_xor(s2, m, 64);
                q2 += __shfl_xor(q2, m, 64);
            }
            if ((d & 63) == 0) { red[wid] = s2; red2[wid] = q2; }
        }
        __syncthreads();
        {
            float tq = red[0] + red[1], tqq = red2[0] + red2[1];
            float muq = tq * (1.f / ND);
            float vq = tqq * (1.f / ND) - muq * muq;
            float rsq = rsqrtf(vq + LN_EPS_C);
            if (half == 0) lnQ[d] = (od - muq) * rsq * lqw[d] + lqb[d];
        }
        __syncthreads();
        // ---- q = lnQ @ Wq, dd-loop split across halves
        {
            float qc = 0.f;
            int dq0 = half * 64;
            for (int dd = dq0; dd < dq0 + 64; ++dd) qc += lnQ[dd] * Wq[(size_t)dd * ND + d];
            qp_[half][d] = qc;
        }
        __syncthreads();
        if (half == 0) qout[(size_t)bk * ND + d] = qp_[0][d] + qp_[1][d];
    }
}

// ---------------------------------------------------------------------------
extern "C" void kernel_launch(void* const* d_in, const int* in_sizes, int n_in,
                              void* d_out, int out_size, void* d_ws, size_t ws_size,
                              hipStream_t stream) {
    const float* inp       = (const float*)d_in[0];
    const float* slot_init = (const float*)d_in[1];
    const float* Wq        = (const float*)d_in[2];
    const float* Wk        = (const float*)d_in[3];
    const float* Wv        = (const float*)d_in[4];
    const float* gru_wi    = (const float*)d_in[5];
    const float* gru_wh    = (const float*)d_in[6];
    const float* gru_bi    = (const float*)d_in[7];
    const float* gru_bh    = (const float*)d_in[8];
    const float* ln_in_w   = (const float*)d_in[9];
    const float* ln_in_b   = (const float*)d_in[10];
    const float* ln_sl_w   = (const float*)d_in[11];
    const float* ln_sl_b   = (const float*)d_in[12];
    const float* ln_ml_w   = (const float*)d_in[13];
    const float* ln_ml_b   = (const float*)d_in[14];
    const float* mlp_w1    = (const float*)d_in[15];
    const float* mlp_b1    = (const float*)d_in[16];
    const float* mlp_w2    = (const float*)d_in[17];
    const float* mlp_b2    = (const float*)d_in[18];

    char* wsb = (char*)d_ws;
    uint* kt2   = (uint*)wsb;                                   // 64 MB
    ushort* vb  = (ushort*)(wsb + (size_t)NB * 64 * NN * 4);    // 64 MB
    ushort* wt2 = vb + (size_t)NB * NN * ND;                    // 128 KB
    float* qb   = (float*)(wt2 + (size_t)NF * NF);
    float* sl   = qb + (size_t)NB * NK * ND;
    float* pU   = sl + (size_t)NB * NK * ND;
    float* pS   = pU + (size_t)NCHUNK * NB * NK * ND;

    init_slots_k<<<(NB * NK * ND) / 256, 256, 0, stream>>>(slot_init, sl);
    wconv_k<<<128, 64, 0, stream>>>(Wk, Wv, wt2);
    ln_project_mfma<<<(NB * NN) / MT, 256, 0, stream>>>(inp, wt2, ln_in_w, ln_in_b, kt2, vb);
    q_kernel<<<NB * NK, 64, 0, stream>>>(sl, Wq, ln_sl_w, ln_sl_b, qb);

    for (int it = 0; it < 3; ++it) {
        attn_kernel<<<dim3(NCHUNK, NB), 256, 0, stream>>>(kt2, vb, qb, pU, pS);
        float* outp = (it == 2) ? (float*)d_out : sl;
        finish_kernel<<<NB * NK, 256, 0, stream>>>(pU, pS, sl, gru_wi, gru_wh,
                                                   gru_bi, gru_bh, ln_ml_w, ln_ml_b,
                                                   mlp_w1, mlp_b1, mlp_w2, mlp_b2, outp,
                                                   Wq, ln_sl_w, ln_sl_b, qb, (it < 2) ? 1 : 0);
    }
}

// Round 4
// 688.801 us; speedup vs baseline: 1.0434x; 1.0434x over previous
//
#include <hip/hip_runtime.h>
#include <math.h>

#define NB 64
#define NN 4096
#define NF 256
#define ND 128
#define NK 8
#define NCHUNK 16
#define CHROWS 256   // NN / NCHUNK
#define MT 64        // rows per block in ln_project_mfma

typedef unsigned int uint;
typedef unsigned short ushort;
typedef __attribute__((ext_vector_type(8))) short short8;
typedef __attribute__((ext_vector_type(4))) float floatx4;

constexpr float LN_EPS_C   = 1e-5f;
constexpr float EPS_ATTN_C = 1e-8f;
constexpr float INV_SCALE  = 0.08838834764831845f; // 1/sqrt(128)

__device__ __forceinline__ float sigmoidf_(float x) { return 1.f / (1.f + expf(-x)); }
__device__ __forceinline__ ushort f2bf(float x) {
    uint u = __float_as_uint(x);
    return (ushort)((u + 0x7FFFu + ((u >> 16) & 1u)) >> 16);
}
__device__ __forceinline__ float bflo(uint u) { return __uint_as_float(u << 16); }
__device__ __forceinline__ float bfhi(uint u) { return __uint_as_float(u & 0xFFFF0000u); }

// ---------------------------------------------------------------- slot init
__global__ void init_slots_k(const float* __restrict__ init, float* __restrict__ slots) {
    int i = blockIdx.x * 256 + threadIdx.x;      // 65536 total
    slots[i] = init[i & (NK * ND - 1)];
}

// ---- weight convert into fragment-contiguous layout:
// wt2 uint4 index = (c16*8 + ks)*64 + lane ; elems j=0..7:
//   col c = c16*16 + (lane&15), f = ks*32 + (lane>>4)*8 + j
// grid: 128 blocks x 64 threads
__global__ void wconv_k(const float* __restrict__ Wk, const float* __restrict__ Wv,
                        ushort* __restrict__ wt2) {
    int idx = blockIdx.x * 64 + threadIdx.x;    // 0..8191 (uint4 index)
    int c16 = idx >> 9, ks = (idx >> 6) & 7, lane = idx & 63;
    int c = c16 * 16 + (lane & 15);
    int f0 = ks * 32 + (lane >> 4) * 8;
    ushort tmp[8];
#pragma unroll
    for (int j = 0; j < 8; ++j) {
        int f = f0 + j;
        float v = (c < ND) ? Wk[(size_t)f * ND + c] : Wv[(size_t)f * ND + (c - ND)];
        tmp[j] = f2bf(v);
    }
    *(uint4*)(wt2 + (size_t)idx * 8) = *(uint4*)tmp;
}

// -------------------- fused LN(inputs) + [x@Wk, x@Wv] via bf16 MFMA
// k out: transposed bf16-pair planes kT2[b][d2][n]  (uint = bf16(2*d2),bf16(2*d2+1))
// v out: row-major bf16 [b][n][d]
// grid: (B*N)/MT = 4096 blocks, 256 threads (4 waves)
__global__ __launch_bounds__(256) void ln_project_mfma(
    const float* __restrict__ inp, const ushort* __restrict__ wt2,
    const float* __restrict__ lw, const float* __restrict__ lb,
    uint* __restrict__ kt2, ushort* __restrict__ vout) {
    __shared__ ushort As[MT][264];   // 33 KB; row stride 528 B
    int t = threadIdx.x;
    size_t rowbase = (size_t)blockIdx.x * MT;
    size_t bidx = rowbase >> 12;          // batch (NN=4096 rows per batch)
    size_t nbase = rowbase & (NN - 1);    // local token base within batch

    // ---- LN phase: 16 threads/row, 16 rows/pass, 4 passes; bf16 to LDS
    {
        int rloc = t >> 4, seg = t & 15;
        const float4* lw4 = (const float4*)lw;
        const float4* lb4 = (const float4*)lb;
#pragma unroll
        for (int p = 0; p < 4; ++p) {
            int r = p * 16 + rloc;
            const float4* rowp = (const float4*)(inp + (rowbase + r) * NF);
            float4 xv[4];
            float sum = 0.f, sq = 0.f;
#pragma unroll
            for (int i = 0; i < 4; ++i) {
                xv[i] = rowp[seg * 4 + i];
                sum += xv[i].x + xv[i].y + xv[i].z + xv[i].w;
                sq += xv[i].x * xv[i].x + xv[i].y * xv[i].y + xv[i].z * xv[i].z + xv[i].w * xv[i].w;
            }
#pragma unroll
            for (int m = 8; m >= 1; m >>= 1) {
                sum += __shfl_xor(sum, m, 64);
                sq  += __shfl_xor(sq,  m, 64);
            }
            float mu = sum * (1.f / NF);
            float var = sq * (1.f / NF) - mu * mu;
            float rs = rsqrtf(var + LN_EPS_C);
#pragma unroll
            for (int i = 0; i < 4; ++i) {
                float4 w = lw4[seg * 4 + i], bb = lb4[seg * 4 + i], x = xv[i];
                float o0 = (x.x - mu) * rs * w.x + bb.x;
                float o1 = (x.y - mu) * rs * w.y + bb.y;
                float o2 = (x.z - mu) * rs * w.z + bb.z;
                float o3 = (x.w - mu) * rs * w.w + bb.w;
                uint2 pk;
                pk.x = (uint)f2bf(o0) | ((uint)f2bf(o1) << 16);
                pk.y = (uint)f2bf(o2) | ((uint)f2bf(o3) << 16);
                *(uint2*)&As[r][seg * 16 + i * 4] = pk;
            }
        }
    }
    __syncthreads();

    // ---- MFMA phase: wave w covers output cols [w*64, w*64+64) of [k|v]
    int w = t >> 6, lane = t & 63;
    int frow = lane & 15, q = lane >> 4;
    floatx4 acc[4][4];
#pragma unroll
    for (int mt = 0; mt < 4; ++mt)
#pragma unroll
        for (int nt = 0; nt < 4; ++nt) acc[mt][nt] = (floatx4)0.f;

#pragma unroll
    for (int ks = 0; ks < 8; ++ks) {
        short8 a[4], b[4];
#pragma unroll
        for (int nt = 0; nt < 4; ++nt)
            b[nt] = *(const short8*)(wt2 + ((((size_t)(w * 4 + nt) * 8 + ks) * 64 + lane) * 8));
#pragma unroll
        for (int mt = 0; mt < 4; ++mt)
            a[mt] = *(const short8*)&As[mt * 16 + frow][ks * 32 + q * 8];
#pragma unroll
        for (int mt = 0; mt < 4; ++mt)
#pragma unroll
            for (int nt = 0; nt < 4; ++nt)
                acc[mt][nt] = __builtin_amdgcn_mfma_f32_16x16x32_bf16(a[mt], b[nt], acc[mt][nt], 0, 0, 0);
    }

    __syncthreads();   // all A-frag reads done before As is reused for v repack

    // C/D layout: col=lane&15 (frow), row=q*4+reg
    if (w < 2) {
        // ---- k epilogue: transpose to kT2[b][d2][n_local] via lane-pair exchange
        int cbase = w * 64;
#pragma unroll
        for (int mt = 0; mt < 4; ++mt)
#pragma unroll
            for (int nt = 0; nt < 4; ++nt) {
                int c = cbase + nt * 16 + frow;
                uint u01 = (uint)f2bf(acc[mt][nt][0]) | ((uint)f2bf(acc[mt][nt][1]) << 16);
                uint u23 = (uint)f2bf(acc[mt][nt][2]) | ((uint)f2bf(acc[mt][nt][3]) << 16);
                uint p01 = __shfl_xor(u01, 1, 64);
                uint p23 = __shfl_xor(u23, 1, 64);
                if ((frow & 1) == 0) {
                    uint4 out;
                    out.x = (u01 & 0xFFFFu) | (p01 << 16);
                    out.y = (u01 >> 16) | (p01 & 0xFFFF0000u);
                    out.z = (u23 & 0xFFFFu) | (p23 << 16);
                    out.w = (u23 >> 16) | (p23 & 0xFFFF0000u);
                    size_t nloc = nbase + mt * 16 + q * 4;
                    *(uint4*)(kt2 + (bidx * 64 + (size_t)(c >> 1)) * NN + nloc) = out;
                }
            }
    } else {
        // ---- v epilogue: park in As (bf16), repack below
        int cbase = (w & 1) * 64;
#pragma unroll
        for (int mt = 0; mt < 4; ++mt)
#pragma unroll
            for (int nt = 0; nt < 4; ++nt) {
                int c = cbase + nt * 16 + frow;
#pragma unroll
                for (int i = 0; i < 4; ++i)
                    As[mt * 16 + q * 4 + i][c] = f2bf(acc[mt][nt][i]);
            }
    }
    __syncthreads();

    // ---- v repack: all 256 threads, coalesced uint4 stores
    {
        int r = t >> 2, part = t & 3;
#pragma unroll
        for (int u = 0; u < 4; ++u) {
            uint4 val = *(const uint4*)&As[r][part * 32 + u * 8];
            *(uint4*)(vout + (rowbase + r) * ND + part * 32 + u * 8) = val;
        }
    }
}

// ------------------------------------------------- q = LN(slots) @ Wq (iter 0)
__global__ __launch_bounds__(64) void q_kernel(
    const float* __restrict__ slots, const float* __restrict__ Wq,
    const float* __restrict__ lw, const float* __restrict__ lb,
    float* __restrict__ qout) {
    __shared__ float sln[ND];
    int bk = blockIdx.x;
    int t = threadIdx.x;
    const float* sp = slots + (size_t)bk * ND;
    float s0 = sp[t], s1 = sp[t + 64];
    float sum = s0 + s1, sq = s0 * s0 + s1 * s1;
#pragma unroll
    for (int m = 1; m < 64; m <<= 1) {
        sum += __shfl_xor(sum, m, 64);
        sq  += __shfl_xor(sq,  m, 64);
    }
    float mu = sum * (1.f / ND);
    float var = sq * (1.f / ND) - mu * mu;
    float rs = rsqrtf(var + LN_EPS_C);
    sln[t]      = (s0 - mu) * rs * lw[t]      + lb[t];
    sln[t + 64] = (s1 - mu) * rs * lw[t + 64] + lb[t + 64];
    __syncthreads();
    float q0 = 0.f, q1 = 0.f;
    for (int dd = 0; dd < ND; ++dd) {
        float v = sln[dd];
        q0 += v * Wq[dd * ND + t];
        q1 += v * Wq[dd * ND + 64 + t];
    }
    qout[(size_t)bk * ND + t] = q0;
    qout[(size_t)bk * ND + 64 + t] = q1;
}

// ------------- attention pass: logits -> softmax(K) -> partial U, S per chunk
// k is transposed bf16-pair planes; v row-major bf16.
// grid: (NCHUNK, NB), 256 threads
// Phase A: k staged through LDS in 4 rounds of 16 planes with register
// prefetch issued AFTER the barrier (latency hides under FMA compute; the
// barrier's vmcnt(0) drain then waits on already-complete loads).
// Phase B: rows split across the 4 waves (v read once per block).
__global__ __launch_bounds__(256) void attn_kernel(
    const uint* __restrict__ kt2, const ushort* __restrict__ vbuf,
    const float* __restrict__ qbuf, float* __restrict__ pU,
    float* __restrict__ pS) {
    __shared__ __align__(16) uint kst[16 * 260];          // 16.6 KB k-stage; aliased as red_s
    __shared__ __align__(16) float attn_s[CHROWS * NK];   // 8 KB
    __shared__ __align__(16) float qs2[64 * 16];          // 4 KB: [d2][kk][2]
    __shared__ float sS[4][NK];
    float* red_s = (float*)kst;                           // [w][16][64] cross-wave U reduce

    int t = threadIdx.x;
    int chunk = blockIdx.x, b = blockIdx.y;
    int w = t >> 6, lane = t & 63;
    int p = t >> 4, sub = t & 15;       // staging: plane p (0..15), token group sub

    // issue round-0 k loads first (latency overlaps qs2 fill)
    const uint* kbase = kt2 + (size_t)b * 64 * NN + (size_t)chunk * CHROWS + sub * 4;
    uint4 pf[4];
#pragma unroll
    for (int i = 0; i < 4; ++i)
        pf[i] = *(const uint4*)(kbase + (size_t)p * NN + i * 64);

    // build qs2[d2*16 + kk*2 + (d&1)] = q[kk][d]
#pragma unroll
    for (int pp = 0; pp < 4; ++pp) {
        int idx = pp * 256 + t;
        int kq = idx >> 7, dq = idx & 127;
        qs2[(dq >> 1) * 16 + kq * 2 + (dq & 1)] = qbuf[(size_t)b * NK * ND + idx];
    }

    // ---- phase A: logits over 4 staging rounds
    float lg[NK];
#pragma unroll
    for (int kk = 0; kk < NK; ++kk) lg[kk] = 0.f;

    for (int r = 0; r < 4; ++r) {
        __syncthreads();                       // prev round consumed (r=0: qs2 ready)
#pragma unroll
        for (int i = 0; i < 4; ++i)
            *(uint4*)(kst + p * 260 + sub * 4 + i * 64) = pf[i];
        __syncthreads();                       // stage visible
        if (r < 3) {
#pragma unroll
            for (int i = 0; i < 4; ++i)
                pf[i] = *(const uint4*)(kbase + (size_t)((r + 1) * 16 + p) * NN + i * 64);
        }
#pragma unroll
        for (int j = 0; j < 16; ++j) {
            uint kr = kst[j * 260 + t];
            float k0 = bflo(kr), k1 = bfhi(kr);
            const float4* qp = (const float4*)(qs2 + (r * 16 + j) * 16);
#pragma unroll
            for (int c = 0; c < 4; ++c) {
                float4 qq = qp[c];
                lg[2 * c]     += k0 * qq.x + k1 * qq.y;
                lg[2 * c + 1] += k0 * qq.z + k1 * qq.w;
            }
        }
    }

    // softmax over K + fused S-partial butterfly
    {
        float mx = -1e30f;
#pragma unroll
        for (int kk = 0; kk < NK; ++kk) { lg[kk] *= INV_SCALE; mx = fmaxf(mx, lg[kk]); }
        float se = 0.f;
        float e[NK];
#pragma unroll
        for (int kk = 0; kk < NK; ++kk) { e[kk] = expf(lg[kk] - mx); se += e[kk]; }
        float inv = 1.f / se;
#pragma unroll
        for (int kk = 0; kk < NK; ++kk) e[kk] = e[kk] * inv + EPS_ATTN_C;
        ((float4*)attn_s)[t * 2]     = make_float4(e[0], e[1], e[2], e[3]);
        ((float4*)attn_s)[t * 2 + 1] = make_float4(e[4], e[5], e[6], e[7]);
#pragma unroll
        for (int m = 1; m < 64; m <<= 1) {
#pragma unroll
            for (int kk = 0; kk < NK; ++kk) e[kk] += __shfl_xor(e[kk], m, 64);
        }
        if (lane == 0) {
#pragma unroll
            for (int kk = 0; kk < NK; ++kk) sS[w][kk] = e[kk];
        }
    }
    __syncthreads();   // attn_s ready; kst reads done -> red_s alias safe

    // ---- phase B: wave w owns rows [w*64, w*64+64); lane -> d pair (d0=2*lane)
    {
        float ua[16];
#pragma unroll
        for (int a = 0; a < 16; ++a) ua[a] = 0.f;
        const uint* vp = (const uint*)(vbuf + ((size_t)b * NN + (size_t)chunk * CHROWS + w * 64) * ND) + lane;
        const float4* ap = (const float4*)(attn_s + (w * 64) * NK);
#pragma unroll 4
        for (int nn2 = 0; nn2 < 64; ++nn2) {
            uint vr = vp[(size_t)nn2 * (ND / 2)];
            float v0 = bflo(vr), v1 = bfhi(vr);
            float4 aA = ap[nn2 * 2];
            float4 aB = ap[nn2 * 2 + 1];
            ua[0]  += aA.x * v0; ua[1]  += aA.x * v1;
            ua[2]  += aA.y * v0; ua[3]  += aA.y * v1;
            ua[4]  += aA.z * v0; ua[5]  += aA.z * v1;
            ua[6]  += aA.w * v0; ua[7]  += aA.w * v1;
            ua[8]  += aB.x * v0; ua[9]  += aB.x * v1;
            ua[10] += aB.y * v0; ua[11] += aB.y * v1;
            ua[12] += aB.z * v0; ua[13] += aB.z * v1;
            ua[14] += aB.w * v0; ua[15] += aB.w * v1;
        }
#pragma unroll
        for (int a = 0; a < 16; ++a) red_s[(w * 16 + a) * 64 + lane] = ua[a];
    }
    __syncthreads();

    // ---- final: cross-wave reduce -> pU; sS reduce -> pS
    {
        size_t pb = ((size_t)chunk * NB + b) * (NK * ND);
#pragma unroll
        for (int i = 0; i < 4; ++i) {
            int slot = i * 256 + t;
            int a = slot >> 6, l = slot & 63;
            float s = red_s[(0 * 16 + a) * 64 + l] + red_s[(1 * 16 + a) * 64 + l] +
                      red_s[(2 * 16 + a) * 64 + l] + red_s[(3 * 16 + a) * 64 + l];
            int kk = a >> 1, r = a & 1;
            pU[pb + (size_t)kk * ND + 2 * l + r] = s;
        }
        if (t < NK) pS[((size_t)chunk * NB + b) * NK + t] = sS[0][t] + sS[1][t] + sS[2][t] + sS[3][t];
    }
}

// -------- reduce partials, normalize, GRU, LN, MLP residual, (+ next q)
// 512 threads: t = (quarter qd, d); serial mat-vec loops split 4-way.
__global__ __launch_bounds__(512) void finish_kernel(
    const float* __restrict__ pU, const float* __restrict__ pS,
    const float* __restrict__ slots_in, const float* __restrict__ wi,
    const float* __restrict__ wh, const float* __restrict__ bi,
    const float* __restrict__ bh, const float* __restrict__ lnw,
    const float* __restrict__ lnb, const float* __restrict__ w1,
    const float* __restrict__ b1, const float* __restrict__ w2,
    const float* __restrict__ b2, float* __restrict__ slots_out,
    const float* __restrict__ Wq, const float* __restrict__ lqw,
    const float* __restrict__ lqb, float* __restrict__ qout, int compute_q) {
    __shared__ float updL[ND], spL[ND], lnL[ND], lnQ[ND], hL[2 * ND];
    __shared__ float Up[4][ND];          // 2 KB
    __shared__ float part[4][6][ND];     // 12 KB GRU partials
    __shared__ float hpart[2][2 * ND];   // 2 KB
    __shared__ float odp[4][ND], qp_[4][ND];
    __shared__ float red[2], red2[2];
    int bk = blockIdx.x;
    int b = bk >> 3, kk = bk & 7;
    int t = threadIdx.x;
    int d = t & 127, qd = t >> 7;

    // ---- U (chunk-split 4-way), S (broadcast)
    float U = 0.f;
#pragma unroll
    for (int c = qd * 4; c < qd * 4 + 4; ++c)
        U += pU[((size_t)c * NB + b) * (NK * ND) + kk * ND + d];
    Up[qd][d] = U;
    float S = 0.f;
#pragma unroll
    for (int c = 0; c < NCHUNK; ++c) S += pS[((size_t)c * NB + b) * NK + kk];
    float spd = slots_in[(size_t)bk * ND + d];
    if (t < ND) spL[d] = spd;
    __syncthreads();
    float upd = (Up[0][d] + Up[1][d] + Up[2][d] + Up[3][d]) / S;
    if (t < ND) updL[d] = upd;
    __syncthreads();

    // ---- GRU: dd-loop split 4-way (32 iters each)
    float a0 = 0.f, a1 = 0.f, a2 = 0.f, a3 = 0.f, a4 = 0.f, a5 = 0.f;
    {
        int dd0 = qd * 32;
        for (int dd = dd0; dd < dd0 + 32; ++dd) {
            float u = updL[dd], s = spL[dd];
            const float* wip = wi + (size_t)dd * 3 * ND;
            const float* whp = wh + (size_t)dd * 3 * ND;
            a0 += u * wip[d];          a3 += s * whp[d];
            a1 += u * wip[ND + d];     a4 += s * whp[ND + d];
            a2 += u * wip[2 * ND + d]; a5 += s * whp[2 * ND + d];
        }
    }
    part[qd][0][d] = a0; part[qd][1][d] = a1; part[qd][2][d] = a2;
    part[qd][3][d] = a3; part[qd][4][d] = a4; part[qd][5][d] = a5;
    __syncthreads();
    float gxr = bi[d]          + part[0][0][d] + part[1][0][d] + part[2][0][d] + part[3][0][d];
    float gxz = bi[ND + d]     + part[0][1][d] + part[1][1][d] + part[2][1][d] + part[3][1][d];
    float gxn = bi[2 * ND + d] + part[0][2][d] + part[1][2][d] + part[2][2][d] + part[3][2][d];
    float ghr = bh[d]          + part[0][3][d] + part[1][3][d] + part[2][3][d] + part[3][3][d];
    float ghz = bh[ND + d]     + part[0][4][d] + part[1][4][d] + part[2][4][d] + part[3][4][d];
    float ghn = bh[2 * ND + d] + part[0][5][d] + part[1][5][d] + part[2][5][d] + part[3][5][d];
    float r_ = sigmoidf_(gxr + ghr);
    float z_ = sigmoidf_(gxz + ghz);
    float nn_ = tanhf(gxn + r_ * ghn);
    float snew = (1.f - z_) * nn_ + z_ * spd;   // replicated across quarters

    // ---- LN(snew): waves 0-1 reduce
    if (t < ND) {
        int wid = d >> 6;
        float sum = snew, sq = snew * snew;
#pragma unroll
        for (int m = 1; m < 64; m <<= 1) {
            sum += __shfl_xor(sum, m, 64);
            sq  += __shfl_xor(sq,  m, 64);
        }
        if ((d & 63) == 0) { red[wid] = sum; red2[wid] = sq; }
    }
    __syncthreads();
    {
        float tot = red[0] + red[1], totq = red2[0] + red2[1];
        float mu = tot * (1.f / ND);
        float var = totq * (1.f / ND) - mu * mu;
        float rs = rsqrtf(var + LN_EPS_C);
        if (t < ND) lnL[d] = (snew - mu) * rs * lnw[d] + lnb[d];
    }
    __syncthreads();

    // ---- MLP1: 256 outputs, 2-way dd split
    {
        int o = t & 255, h = t >> 8;
        float h0 = 0.f;
        for (int dd = h * 64; dd < h * 64 + 64; ++dd)
            h0 += lnL[dd] * w1[(size_t)dd * 2 * ND + o];
        hpart[h][o] = h0;
    }
    __syncthreads();
    if (t < 2 * ND) hL[t] = fmaxf(b1[t] + hpart[0][t] + hpart[1][t], 0.f);
    __syncthreads();

    // ---- MLP2: j-loop split 4-way
    {
        float od_p = 0.f;
        int j0 = qd * 64;
        for (int j = j0; j < j0 + 64; ++j) od_p += hL[j] * w2[(size_t)j * ND + d];
        odp[qd][d] = od_p;
    }
    __syncthreads();
    float od = snew + b2[d] + odp[0][d] + odp[1][d] + odp[2][d] + odp[3][d];
    if (t < ND) slots_out[(size_t)bk * ND + d] = od;

    if (compute_q) {
        // ---- LN(od) (red/red2 reusable: barriers have passed since last read)
        if (t < ND) {
            int wid = d >> 6;
            float s2 = od, q2 = od * od;
#pragma unroll
            for (int m = 1; m < 64; m <<= 1) {
                s2 += __shfl_xor(s2, m, 64);
                q2 += __shfl_xor(q2, m, 64);
            }
            if ((d & 63) == 0) { red[wid] = s2; red2[wid] = q2; }
        }
        __syncthreads();
        {
            float tq = red[0] + red[1], tqq = red2[0] + red2[1];
            float muq = tq * (1.f / ND);
            float vq = tqq * (1.f / ND) - muq * muq;
            float rsq = rsqrtf(vq + LN_EPS_C);
            if (t < ND) lnQ[d] = (od - muq) * rsq * lqw[d] + lqb[d];
        }
        __syncthreads();
        // ---- q = lnQ @ Wq, dd-loop split 4-way
        {
            float qc = 0.f;
            int dq0 = qd * 32;
            for (int dd = dq0; dd < dq0 + 32; ++dd) qc += lnQ[dd] * Wq[(size_t)dd * ND + d];
            qp_[qd][d] = qc;
        }
        __syncthreads();
        if (t < ND) qout[(size_t)bk * ND + d] = qp_[0][d] + qp_[1][d] + qp_[2][d] + qp_[3][d];
    }
}

// ---------------------------------------------------------------------------
extern "C" void kernel_launch(void* const* d_in, const int* in_sizes, int n_in,
                              void* d_out, int out_size, void* d_ws, size_t ws_size,
                              hipStream_t stream) {
    const float* inp       = (const float*)d_in[0];
    const float* slot_init = (const float*)d_in[1];
    const float* Wq        = (const float*)d_in[2];
    const float* Wk        = (const float*)d_in[3];
    const float* Wv        = (const float*)d_in[4];
    const float* gru_wi    = (const float*)d_in[5];
    const float* gru_wh    = (const float*)d_in[6];
    const float* gru_bi    = (const float*)d_in[7];
    const float* gru_bh    = (const float*)d_in[8];
    const float* ln_in_w   = (const float*)d_in[9];
    const float* ln_in_b   = (const float*)d_in[10];
    const float* ln_sl_w   = (const float*)d_in[11];
    const float* ln_sl_b   = (const float*)d_in[12];
    const float* ln_ml_w   = (const float*)d_in[13];
    const float* ln_ml_b   = (const float*)d_in[14];
    const float* mlp_w1    = (const float*)d_in[15];
    const float* mlp_b1    = (const float*)d_in[16];
    const float* mlp_w2    = (const float*)d_in[17];
    const float* mlp_b2    = (const float*)d_in[18];

    char* wsb = (char*)d_ws;
    uint* kt2   = (uint*)wsb;                                   // 64 MB
    ushort* vb  = (ushort*)(wsb + (size_t)NB * 64 * NN * 4);    // 64 MB
    ushort* wt2 = vb + (size_t)NB * NN * ND;                    // 128 KB
    float* qb   = (float*)(wt2 + (size_t)NF * NF);
    float* sl   = qb + (size_t)NB * NK * ND;
    float* pU   = sl + (size_t)NB * NK * ND;
    float* pS   = pU + (size_t)NCHUNK * NB * NK * ND;

    init_slots_k<<<(NB * NK * ND) / 256, 256, 0, stream>>>(slot_init, sl);
    wconv_k<<<128, 64, 0, stream>>>(Wk, Wv, wt2);
    ln_project_mfma<<<(NB * NN) / MT, 256, 0, stream>>>(inp, wt2, ln_in_w, ln_in_b, kt2, vb);
    q_kernel<<<NB * NK, 64, 0, stream>>>(sl, Wq, ln_sl_w, ln_sl_b, qb);

    for (int it = 0; it < 3; ++it) {
        attn_kernel<<<dim3(NCHUNK, NB), 256, 0, stream>>>(kt2, vb, qb, pU, pS);
        float* outp = (it == 2) ? (float*)d_out : sl;
        finish_kernel<<<NB * NK, 512, 0, stream>>>(pU, pS, sl, gru_wi, gru_wh,
                                                   gru_bi, gru_bh, ln_ml_w, ln_ml_b,
                                                   mlp_w1, mlp_b1, mlp_w2, mlp_b2, outp,
                                                   Wq, ln_sl_w, ln_sl_b, qb, (it < 2) ? 1 : 0);
    }
}